// Round 1
// 1079.256 us; speedup vs baseline: 1.2675x; 1.2675x over previous
//
#include <hip/hip_runtime.h>

#define BB 32
#define NN 8192
#define DD 256
#define KK 16

typedef __bf16  bf16x8 __attribute__((ext_vector_type(8)));
typedef float   f32x4  __attribute__((ext_vector_type(4)));
typedef unsigned short us8 __attribute__((ext_vector_type(8)));

__device__ __forceinline__ unsigned short f2bf(float f) {
  unsigned u = __builtin_bit_cast(unsigned, f);
  u += 0x7fffu + ((u >> 16) & 1u);
  return (unsigned short)(u >> 16);
}
__device__ __forceinline__ float bf2f(unsigned short h) {
  unsigned u = ((unsigned)h) << 16;
  return __builtin_bit_cast(float, u);
}
__device__ __forceinline__ float sigm(float x) { return 1.f / (1.f + __expf(-x)); }
__device__ __forceinline__ float tanh_fast(float x) { return 1.f - 2.f / (__expf(2.f * x) + 1.f); }

// async global->LDS, 16B per lane. LDS dest = uniform base + lane*16.
__device__ __forceinline__ void gl2lds16(const void* g, void* l) {
  __builtin_amdgcn_global_load_lds((const __attribute__((address_space(1))) unsigned int*)g,
                                   (__attribute__((address_space(3))) unsigned int*)l, 16, 0, 0);
}

// ---------------- init: cast Wk|Wv -> bf16 [512][256], broadcast slot_inits ----------------
__global__ __launch_bounds__(256) void k_init(const float* __restrict__ Wk, const float* __restrict__ Wv,
                                              const float* __restrict__ sinit,
                                              unsigned short* __restrict__ Wkvb, float* __restrict__ slots) {
  int idx = blockIdx.x * 256 + threadIdx.x;  // 0..131071
  int row = idx >> 8, col = idx & 255;
  float w = (row < 256) ? Wk[row * 256 + col] : Wv[(row - 256) * 256 + col];
  Wkvb[idx] = f2bf(w);
  slots[idx] = sinit[(row & 15) * 256 + col];
}

// ---------------- fused LN + K/V projection GEMM: LDS-staged weights, double-buffered ----------------
// block = 256 rows (4 waves x 4 strips of 16); weights staged in 64-out chunks (32KB, pair-padded).
// Pipeline: one barrier per chunk; stage(c+1) issued AFTER the barrier so its drain overlaps compute(c).
__global__ __launch_bounds__(256) void k_proj(const float* __restrict__ X, const float* __restrict__ lng,
                                              const float* __restrict__ lnb,
                                              const unsigned short* __restrict__ Wkvb,
                                              unsigned short* __restrict__ kv) {
  __shared__ __attribute__((aligned(16))) char bt[2][33280];  // 32 pairs * 1040B each
  const int wave = threadIdx.x >> 6, lane = threadIdx.x & 63;
  const int c16 = lane & 15, quad = lane >> 4;
  const int row0 = blockIdx.x * 256 + wave * 64;

  bf16x8 af[4][8];
#pragma unroll
  for (int s = 0; s < 4; ++s) {
    const int row = row0 + s * 16 + c16;
    const float* xr = X + (long)row * 256;
    float v[8][8];
    float sum = 0.f, sq = 0.f;
#pragma unroll
    for (int fi = 0; fi < 8; ++fi) {
      const float4 a0 = *(const float4*)(xr + fi * 32 + quad * 8);
      const float4 a1 = *(const float4*)(xr + fi * 32 + quad * 8 + 4);
      v[fi][0] = a0.x; v[fi][1] = a0.y; v[fi][2] = a0.z; v[fi][3] = a0.w;
      v[fi][4] = a1.x; v[fi][5] = a1.y; v[fi][6] = a1.z; v[fi][7] = a1.w;
      sum += a0.x + a0.y + a0.z + a0.w + a1.x + a1.y + a1.z + a1.w;
      sq += a0.x * a0.x + a0.y * a0.y + a0.z * a0.z + a0.w * a0.w +
            a1.x * a1.x + a1.y * a1.y + a1.z * a1.z + a1.w * a1.w;
    }
    sum += __shfl_xor(sum, 16); sum += __shfl_xor(sum, 32);
    sq  += __shfl_xor(sq, 16);  sq  += __shfl_xor(sq, 32);
    const float mean = sum * (1.f / 256.f);
    const float rstd = rsqrtf(sq * (1.f / 256.f) - mean * mean + 1e-5f);
#pragma unroll
    for (int fi = 0; fi < 8; ++fi) {
      const int dbase = fi * 32 + quad * 8;
      const float4 g0 = *(const float4*)(lng + dbase), g1 = *(const float4*)(lng + dbase + 4);
      const float4 b0 = *(const float4*)(lnb + dbase), b1 = *(const float4*)(lnb + dbase + 4);
      us8 t;
      t[0] = f2bf((v[fi][0] - mean) * rstd * g0.x + b0.x);
      t[1] = f2bf((v[fi][1] - mean) * rstd * g0.y + b0.y);
      t[2] = f2bf((v[fi][2] - mean) * rstd * g0.z + b0.z);
      t[3] = f2bf((v[fi][3] - mean) * rstd * g0.w + b0.w);
      t[4] = f2bf((v[fi][4] - mean) * rstd * g1.x + b1.x);
      t[5] = f2bf((v[fi][5] - mean) * rstd * g1.y + b1.y);
      t[6] = f2bf((v[fi][6] - mean) * rstd * g1.z + b1.z);
      t[7] = f2bf((v[fi][7] - mean) * rstd * g1.w + b1.w);
      af[s][fi] = __builtin_bit_cast(bf16x8, t);
    }
  }

  // stage chunk 0 (64 outs = 32 row-pairs; each inst DMAs 1KB = 2 weight rows)
  {
    const char* gw = (const char*)Wkvb;
#pragma unroll
    for (int i = 0; i < 8; ++i) {
      const int p = wave * 8 + i;
      gl2lds16(gw + p * 1024 + lane * 16, &bt[0][p * 1040]);
    }
  }
#pragma unroll 1
  for (int c = 0; c < 8; ++c) {
    __syncthreads();  // drains stage(c); everyone past chunk c-1 reads
    if (c < 7) {
      const char* gw = (const char*)Wkvb + (c + 1) * 32768;
#pragma unroll
      for (int i = 0; i < 8; ++i) {
        const int p = wave * 8 + i;
        gl2lds16(gw + p * 1024 + lane * 16, &bt[(c + 1) & 1][p * 1040]);
      }
    }
    const char* bb = bt[c & 1];
#pragma unroll 1
    for (int ot = 0; ot < 4; ++ot) {
      const int tl = ot * 16 + c16;
      const char* bp = bb + (tl >> 1) * 1040 + (tl & 1) * 512 + quad * 16;
      f32x4 acc[4];
#pragma unroll
      for (int s = 0; s < 4; ++s) { acc[s][0] = 0.f; acc[s][1] = 0.f; acc[s][2] = 0.f; acc[s][3] = 0.f; }
#pragma unroll
      for (int fi = 0; fi < 8; ++fi) {
        const bf16x8 bfrag = *(const bf16x8*)(bp + fi * 64);
#pragma unroll
        for (int s = 0; s < 4; ++s)
          acc[s] = __builtin_amdgcn_mfma_f32_16x16x32_bf16(af[s][fi], bfrag, acc[s], 0, 0, 0);
      }
      const int col = c * 64 + ot * 16 + c16;
#pragma unroll
      for (int s = 0; s < 4; ++s) {
#pragma unroll
        for (int r = 0; r < 4; ++r) {
          kv[(long)(row0 + s * 16 + quad * 4 + r) * 512 + col] = f2bf(acc[s][r]);
        }
      }
    }
  }
}

// ---------------- q = slots @ Wq.T  (fp32, cast to bf16) ----------------
__global__ __launch_bounds__(256) void k_qproj(const float* __restrict__ slots, const float* __restrict__ Wq,
                                               unsigned short* __restrict__ qb) {
  __shared__ float srow[256];
  const int row = blockIdx.x, t = threadIdx.x;
  srow[t] = slots[row * 256 + t];
  __syncthreads();
  float acc = 0.f;
  const float4* wr = (const float4*)(Wq + t * 256);
#pragma unroll 8
  for (int i = 0; i < 64; ++i) {
    float4 w = wr[i];
    float4 s = *(const float4*)(srow + i * 4);
    acc += w.x * s.x + w.y * s.y + w.z * s.z + w.w * s.w;
  }
  qb[row * 256 + t] = f2bf(acc);
}

// ---------------- fused attention iteration ----------------
// grid = 32 b * 8 slabs; slab = 1024 tokens = 16 chunks of 64 tokens.
// Full kv rows (K+V halves) staged per chunk into a double buffer (64 pairs * 1040B).
// ONE barrier per chunk; stage(c+1) issued right after it so the DMA overlaps phase A+B of chunk c.
// LDS: 2*66560 (stage) + 4096 (attn) = 137216 B -> 1 block/CU; pipelining, not TLP, hides latency.
__device__ __forceinline__ void stage_chunk64(const char* gk, char* buf, int wave, int lane) {
#pragma unroll
  for (int i = 0; i < 16; ++i) {
    const int p = wave * 16 + i;        // pair 0..63: 0-31 = K halves, 32-63 = V halves
    const int tp = p & 31;              // token pair within chunk
    const int vh = (p >> 5) * 512;      // 0 for K half, 512 for V half
    gl2lds16(gk + (2 * tp + (lane >> 5)) * 1024 + vh + (lane & 31) * 16, buf + p * 1040);
  }
}

template <bool FINAL>
__global__ __launch_bounds__(256) void k_attn(const unsigned short* __restrict__ kv,
                                              const unsigned short* __restrict__ qb,
                                              float* __restrict__ updates, float* __restrict__ aw,
                                              float* __restrict__ winning, float* __restrict__ total) {
  __shared__ __attribute__((aligned(16))) char sbuf[2][66560];  // 64 pairs * 1040B each
  __shared__ float lds_attn[4][16][16];
  const int wave = threadIdx.x >> 6, lane = threadIdx.x & 63;
  const int c16 = lane & 15, quad = lane >> 4;
  const int b = blockIdx.x >> 3, slab = blockIdx.x & 7;

  bf16x8 qa[8];
  const unsigned short* qrow = qb + (b * 16 + c16) * 256 + quad * 8;
#pragma unroll
  for (int fi = 0; fi < 8; ++fi) qa[fi] = *(const bf16x8*)(qrow + fi * 32);

  float acc[16][4];
#pragma unroll
  for (int s = 0; s < 16; ++s) { acc[s][0] = 0.f; acc[s][1] = 0.f; acc[s][2] = 0.f; acc[s][3] = 0.f; }

  const char* gk0 = (const char*)kv + ((long)b * 8192 + (long)slab * 1024) * 1024;

  stage_chunk64(gk0, sbuf[0], wave, lane);  // prologue: chunk 0 in flight

#pragma unroll 1
  for (int ch = 0; ch < 16; ++ch) {
    __syncthreads();  // drains stage(ch); all waves done reading buf[(ch+1)&1] (chunk ch-1)
    if (ch < 15) stage_chunk64(gk0 + (ch + 1) * 65536, sbuf[(ch + 1) & 1], wave, lane);
    const char* bb = sbuf[ch & 1];

    // ---- phase A: logits MFMA + softmax over slots (per token) ----
    const int tl = wave * 16 + c16;
    const char* kp = bb + (tl >> 1) * 1040 + (tl & 1) * 512 + quad * 16;
    f32x4 c = {0.f, 0.f, 0.f, 0.f};
#pragma unroll
    for (int fi = 0; fi < 8; ++fi) {
      const bf16x8 bfrag = *(const bf16x8*)(kp + fi * 64);
      c = __builtin_amdgcn_mfma_f32_16x16x32_bf16(qa[fi], bfrag, c, 0, 0, 0);
    }
    float l[4];
#pragma unroll
    for (int r = 0; r < 4; ++r) l[r] = c[r] * 0.0625f;  // * D^-0.5
    float m = l[0]; int mi = quad * 4;
#pragma unroll
    for (int r = 1; r < 4; ++r) { if (l[r] > m) { m = l[r]; mi = quad * 4 + r; } }
#pragma unroll
    for (int off = 16; off < 64; off <<= 1) {
      float om = __shfl_xor(m, off); int oi = __shfl_xor(mi, off);
      if (om > m || (om == m && oi < mi)) { m = om; mi = oi; }
    }
    float e[4], ssum = 0.f;
#pragma unroll
    for (int r = 0; r < 4; ++r) { e[r] = __expf(l[r] - m); ssum += e[r]; }
    ssum += __shfl_xor(ssum, 16); ssum += __shfl_xor(ssum, 32);
    const float inv = 1.f / ssum;
    float a[4];
#pragma unroll
    for (int r = 0; r < 4; ++r) a[r] = e[r] * inv;

    if (FINAL) {
      const int tg = slab * 1024 + ch * 64 + wave * 16 + c16;
      *(float4*)(aw + (long)(b * 8192 + tg) * 16 + quad * 4) = make_float4(a[0], a[1], a[2], a[3]);
      float ts[4] = {a[0], a[1], a[2], a[3]};
#pragma unroll
      for (int off = 1; off < 16; off <<= 1) {
#pragma unroll
        for (int r = 0; r < 4; ++r) ts[r] += __shfl_xor(ts[r], off);
      }
      if (c16 == 0) {
#pragma unroll
        for (int r = 0; r < 4; ++r) atomicAdd(&total[b * 16 + quad * 4 + r], ts[r]);
      }
      if (quad == 0) atomicAdd(&winning[b * 16 + mi], inv);  // max attn = exp(0)*inv
    }

    // wave-private: wave w only ever reads lds_attn[w][*][*] (no barrier needed)
    *(float4*)&lds_attn[wave][c16][quad * 4] = make_float4(a[0], a[1], a[2], a[3]);

    // ---- phase B: acc[slot][dl] += attn[slot,n] * v[n, lane*4+dl], wave's own 16 tokens ----
#pragma unroll 4
    for (int nn = 0; nn < 16; ++nn) {
      const int n = wave * 16 + nn;
      const char* vp = bb + (32 + (n >> 1)) * 1040 + (n & 1) * 512 + lane * 8;
      const ushort4 vv = *(const ushort4*)vp;
      const float v0 = bf2f(vv.x), v1 = bf2f(vv.y), v2 = bf2f(vv.z), v3 = bf2f(vv.w);
      const float4 a0 = *(const float4*)&lds_attn[wave][nn][0];
      const float4 a1 = *(const float4*)&lds_attn[wave][nn][4];
      const float4 a2 = *(const float4*)&lds_attn[wave][nn][8];
      const float4 a3 = *(const float4*)&lds_attn[wave][nn][12];
      const float as[16] = {a0.x, a0.y, a0.z, a0.w, a1.x, a1.y, a1.z, a1.w,
                            a2.x, a2.y, a2.z, a2.w, a3.x, a3.y, a3.z, a3.w};
#pragma unroll
      for (int s = 0; s < 16; ++s) {
        acc[s][0] = fmaf(as[s], v0, acc[s][0]);
        acc[s][1] = fmaf(as[s], v1, acc[s][1]);
        acc[s][2] = fmaf(as[s], v2, acc[s][2]);
        acc[s][3] = fmaf(as[s], v3, acc[s][3]);
      }
    }
  }

  // ---- cross-wave reduce through the (now dead) stage buffer: no LDS atomics ----
  __syncthreads();
  float* part = (float*)sbuf;  // [4 waves][16 slots][256 d] fp32 = 64KB, fits in sbuf[0]
#pragma unroll
  for (int s = 0; s < 16; ++s)
    *(float4*)&part[(wave * 16 + s) * 256 + lane * 4] =
        make_float4(acc[s][0], acc[s][1], acc[s][2], acc[s][3]);
  __syncthreads();
  float* ub = updates + b * (KK * DD);
#pragma unroll
  for (int i = 0; i < 16; ++i) {
    const int idx = i * 256 + threadIdx.x;
    atomicAdd(&ub[idx], part[idx] + part[4096 + idx] + part[8192 + idx] + part[12288 + idx]);
  }
}

// ---------------- GRU + residual MLP slot update (fp32), 4 rows per block ----------------
__global__ __launch_bounds__(256) void k_slotup(const float* __restrict__ updates, float* __restrict__ slots,
                                                const float* __restrict__ wih, const float* __restrict__ whh,
                                                const float* __restrict__ bih, const float* __restrict__ bhh,
                                                const float* __restrict__ mlng, const float* __restrict__ mlnb,
                                                const float* __restrict__ w1, const float* __restrict__ b1,
                                                const float* __restrict__ w2, const float* __restrict__ b2) {
  __shared__ float su[4][256];
  __shared__ float ss[4][256];
  __shared__ float sn[4][256];
  __shared__ float h1s[4][512];
  __shared__ float mv[8];
  const int t = threadIdx.x;
  const int r0 = blockIdx.x * 4;
#pragma unroll
  for (int r = 0; r < 4; ++r) {
    su[r][t] = updates[(r0 + r) * 256 + t];
    ss[r][t] = slots[(r0 + r) * 256 + t];
  }
  __syncthreads();
  float giv[3][4], ghv[3][4];
#pragma unroll 1
  for (int p = 0; p < 3; ++p) {
    const int o = p * 256 + t;
    float ai[4], ah[4];
    const float bi = bih[o], bh = bhh[o];
#pragma unroll
    for (int r = 0; r < 4; ++r) { ai[r] = bi; ah[r] = bh; }
    const float4* wi = (const float4*)(wih + o * 256);
    const float4* wh = (const float4*)(whh + o * 256);
#pragma unroll 4
    for (int i = 0; i < 64; ++i) {
      const float4 a = wi[i], hh = wh[i];
#pragma unroll
      for (int r = 0; r < 4; ++r) {
        const float4 u = *(const float4*)&su[r][i * 4];
        const float4 s = *(const float4*)&ss[r][i * 4];
        ai[r] += a.x * u.x + a.y * u.y + a.z * u.z + a.w * u.w;
        ah[r] += hh.x * s.x + hh.y * s.y + hh.z * s.z + hh.w * s.w;
      }
    }
#pragma unroll
    for (int r = 0; r < 4; ++r) { giv[p][r] = ai[r]; ghv[p][r] = ah[r]; }
  }
#pragma unroll
  for (int r = 0; r < 4; ++r) {
    const float rg = sigm(giv[0][r] + ghv[0][r]);
    const float z = sigm(giv[1][r] + ghv[1][r]);
    const float ng = tanh_fast(giv[2][r] + rg * ghv[2][r]);
    sn[r][t] = (1.f - z) * ng + z * ss[r][t];
  }
  __syncthreads();
  const int wv = t >> 6, ln = t & 63;
  {
    const float4 x = *(const float4*)&sn[wv][ln * 4];
    float s = x.x + x.y + x.z + x.w;
    float q = x.x * x.x + x.y * x.y + x.z * x.z + x.w * x.w;
#pragma unroll
    for (int off = 1; off < 64; off <<= 1) { s += __shfl_xor(s, off); q += __shfl_xor(q, off); }
    if (ln == 0) {
      const float mean = s * (1.f / 256.f);
      mv[wv * 2] = mean;
      mv[wv * 2 + 1] = rsqrtf(q * (1.f / 256.f) - mean * mean + 1e-5f);
    }
  }
  __syncthreads();
  const float gt = mlng[t], btv = mlnb[t];
#pragma unroll
  for (int r = 0; r < 4; ++r) ss[r][t] = (sn[r][t] - mv[r * 2]) * mv[r * 2 + 1] * gt + btv;
  __syncthreads();
#pragma unroll 1
  for (int p = 0; p < 2; ++p) {
    const int o = p * 256 + t;
    float a1v[4];
    const float bb1 = b1[o];
#pragma unroll
    for (int r = 0; r < 4; ++r) a1v[r] = bb1;
    const float4* wr = (const float4*)(w1 + o * 256);
#pragma unroll 4
    for (int i = 0; i < 64; ++i) {
      const float4 w = wr[i];
#pragma unroll
      for (int r = 0; r < 4; ++r) {
        const float4 hv = *(const float4*)&ss[r][i * 4];
        a1v[r] += w.x * hv.x + w.y * hv.y + w.z * hv.z + w.w * hv.w;
      }
    }
#pragma unroll
    for (int r = 0; r < 4; ++r) h1s[r][o] = fmaxf(a1v[r], 0.f);
  }
  __syncthreads();
  float a2[4];
  const float bb2 = b2[t];
#pragma unroll
  for (int r = 0; r < 4; ++r) a2[r] = bb2;
  const float4* w2r = (const float4*)(w2 + t * 512);
#pragma unroll 4
  for (int i = 0; i < 128; ++i) {
    const float4 w = w2r[i];
#pragma unroll
    for (int r = 0; r < 4; ++r) {
      const float4 hv = *(const float4*)&h1s[r][i * 4];
      a2[r] += w.x * hv.x + w.y * hv.y + w.z * hv.z + w.w * hv.w;
    }
  }
#pragma unroll
  for (int r = 0; r < 4; ++r) slots[(r0 + r) * 256 + t] = sn[r][t] + a2[r];
}

// ---------------- heads: selection + quality + output writes ----------------
__global__ __launch_bounds__(256) void k_final(const float* __restrict__ slots, const float* __restrict__ winning,
                                               const float* __restrict__ total, const float* __restrict__ conf,
                                               const float* __restrict__ sw1, const float* __restrict__ sb1,
                                               const float* __restrict__ sw2, const float* __restrict__ sb2,
                                               const float* __restrict__ qw1, const float* __restrict__ qb1,
                                               const float* __restrict__ qw2, const float* __restrict__ qb2,
                                               float* __restrict__ out_slots, float* __restrict__ out_mask,
                                               float* __restrict__ out_quality) {
  __shared__ float srow[256];
  __shared__ float sh[128];
  __shared__ float lq[64];
  const int row = blockIdx.x, t = threadIdx.x;
  srow[t] = slots[row * 256 + t];
  __syncthreads();
  if (t < 128) {
    float acc = sb1[t];
    const float4* wr = (const float4*)(sw1 + t * 256);
#pragma unroll 8
    for (int i = 0; i < 64; ++i) {
      const float4 w = wr[i];
      const float4 s = *(const float4*)(srow + i * 4);
      acc += w.x * s.x + w.y * s.y + w.z * s.z + w.w * s.w;
    }
    sh[t] = fmaxf(acc, 0.f);
  } else if (t < 192) {
    const int o = t - 128;
    float acc = qb1[o];
    const float4* wr = (const float4*)(qw1 + o * 256);
#pragma unroll 8
    for (int i = 0; i < 64; ++i) {
      const float4 w = wr[i];
      const float4 s = *(const float4*)(srow + i * 4);
      acc += w.x * s.x + w.y * s.y + w.z * s.z + w.w * s.w;
    }
    lq[o] = fmaxf(acc, 0.f);
  }
  __syncthreads();
  if (t < 64) {
    float a = sh[t] * sw2[t] + sh[t + 64] * sw2[t + 64];
    float bq = lq[t] * qw2[t];
#pragma unroll
    for (int off = 1; off < 64; off <<= 1) { a += __shfl_xor(a, off); bq += __shfl_xor(bq, off); }
    if (t == 0) {
      const float sel_logit = a + sb2[0];
      const float learned = sigm(bq + qb2[0]);
      const float attq = winning[row] / (total[row] + 1e-8f);
      float qual = 0.4f * attq + 0.4f * learned;
      qual = qual * 0.2f + conf[row] * 0.8f;
      out_quality[row] = qual;
      out_mask[row] = (sel_logit > 0.f && qual > 0.3f) ? 1.f : 0.f;  // sigmoid(x)>0.5 <=> x>0
    }
  }
  out_slots[row * 256 + t] = srow[t];
}

extern "C" void kernel_launch(void* const* d_in, const int* in_sizes, int n_in,
                              void* d_out, int out_size, void* d_ws, size_t ws_size,
                              hipStream_t stream) {
  const float* X = (const float*)d_in[0];
  const float* conf = (const float*)d_in[1];
  const float* sinit = (const float*)d_in[2];
  const float* lng = (const float*)d_in[3];
  const float* lnb = (const float*)d_in[4];
  const float* Wq = (const float*)d_in[5];
  const float* Wk = (const float*)d_in[6];
  const float* Wv = (const float*)d_in[7];
  const float* wih = (const float*)d_in[8];
  const float* whh = (const float*)d_in[9];
  const float* bih = (const float*)d_in[10];
  const float* bhh = (const float*)d_in[11];
  const float* mlng = (const float*)d_in[12];
  const float* mlnb = (const float*)d_in[13];
  const float* w1 = (const float*)d_in[14];
  const float* b1 = (const float*)d_in[15];
  const float* w2 = (const float*)d_in[16];
  const float* b2 = (const float*)d_in[17];
  const float* sw1 = (const float*)d_in[18];
  const float* sb1 = (const float*)d_in[19];
  const float* sw2 = (const float*)d_in[20];
  const float* sb2 = (const float*)d_in[21];
  const float* qw1 = (const float*)d_in[22];
  const float* qb1 = (const float*)d_in[23];
  const float* qw2 = (const float*)d_in[24];
  const float* qb2 = (const float*)d_in[25];

  char* w = (char*)d_ws;
  unsigned short* kv = (unsigned short*)(w);                    // 268435456 B
  unsigned short* Wkvb = (unsigned short*)(w + 268435456);      // 262144 B
  unsigned short* qb = (unsigned short*)(w + 268697600);        // 262144 B
  float* slots = (float*)(w + 268959744);                       // 524288 B
  float* updates = (float*)(w + 269484032);                     // 524288 B
  float* winning = (float*)(w + 270008320);                     // 2048 B
  float* total = (float*)(w + 270010368);                       // 2048 B

  float* out_slots = (float*)d_out;                   // [32,16,256]
  float* out_mask = out_slots + 131072;               // [32,16]
  float* out_quality = out_mask + 512;                // [32,16]
  float* aw = out_quality + 512;                      // [32,8192,16]

  k_init<<<512, 256, 0, stream>>>(Wk, Wv, sinit, Wkvb, slots);
  k_proj<<<1024, 256, 0, stream>>>(X, lng, lnb, Wkvb, kv);
  for (int it = 0; it < 3; ++it) {
    k_qproj<<<512, 256, 0, stream>>>(slots, Wq, qb);
    hipMemsetAsync(updates, 0, 512 * 256 * 4, stream);
    if (it == 2) {
      hipMemsetAsync(winning, 0, 2048, stream);
      hipMemsetAsync(total, 0, 2048, stream);
      k_attn<true><<<256, 256, 0, stream>>>(kv, qb, updates, aw, winning, total);
    } else {
      k_attn<false><<<256, 256, 0, stream>>>(kv, qb, updates, nullptr, nullptr, nullptr);
    }
    k_slotup<<<128, 256, 0, stream>>>(updates, slots, wih, whh, bih, bhh, mlng, mlnb, w1, b1, w2, b2);
  }
  k_final<<<512, 256, 0, stream>>>(slots, winning, total, conf, sw1, sb1, sw2, sb2,
                                   qw1, qb1, qw2, qb2, out_slots, out_mask, out_quality);
}